// Round 1
// baseline (514.127 us; speedup 1.0000x reference)
//
#include <hip/hip_runtime.h>

#define D_MODEL 2048
#define SEQ     2048
#define NB      2
#define NH      16
#define DH      128
#define MROWS   (NB*SEQ)   /* 4096 */
#define GK      2048       /* K dim of all GEMMs */

typedef __bf16 bf16x8 __attribute__((ext_vector_type(8)));
typedef float  f32x4  __attribute__((ext_vector_type(4)));
typedef unsigned short ushort8 __attribute__((ext_vector_type(8)));

__device__ __forceinline__ unsigned short f2bf(float f) {
  unsigned int u = __float_as_uint(f);
  u += 0x7FFFu + ((u >> 16) & 1u);
  return (unsigned short)(u >> 16);
}

__device__ __forceinline__ void gload16(void* lds, const void* g) {
  __builtin_amdgcn_global_load_lds(
      (__attribute__((address_space(1))) void*)(g),
      (__attribute__((address_space(3))) void*)(lds), 16, 0, 0);
}

/* ---------------- fp32 -> bf16 cast, 8 elems/thread ---------------- */
__global__ __launch_bounds__(256) void cast_f32_bf16(
    const float* __restrict__ in, unsigned short* __restrict__ out) {
  int i = blockIdx.x * 256 + threadIdx.x;
  const float4* p = (const float4*)in;
  float4 a = p[2*i], b = p[2*i+1];
  ushort8 o;
  o[0]=f2bf(a.x); o[1]=f2bf(a.y); o[2]=f2bf(a.z); o[3]=f2bf(a.w);
  o[4]=f2bf(b.x); o[5]=f2bf(b.y); o[6]=f2bf(b.z); o[7]=f2bf(b.w);
  ((ushort8*)out)[i] = o;
}

/* ---------------- GEMM: C[M,N] = A[M,K] * B[N,K]^T + bias ----------------
   m97 structure: 128x128 tile, BK=32, 4 waves (each 64x64 = 4x4 frags of
   16x16x32), global_load_lds width 16, 2 barriers per K-step.
   mode 0: bf16 scatter to head-major [b,h,s,d] (QKV).  mode 1: fp32 [M,N]. */
__global__ __launch_bounds__(256) void gemm_bt(
    const unsigned short* __restrict__ A,
    const unsigned short* __restrict__ B,
    const float* __restrict__ bias,
    unsigned short* __restrict__ outb,
    float* __restrict__ outf,
    int mode)
{
  __shared__ unsigned short As[128*32];
  __shared__ unsigned short Bs[128*32];

  const int tid  = threadIdx.x;
  const int lane = tid & 63;
  const int wid  = tid >> 6;
  const int la   = lane & 15, hi = lane >> 4;
  const int wr   = wid >> 1,  wc = wid & 1;
  const int row0 = blockIdx.y * 128;
  const int col0 = blockIdx.x * 128;

  const unsigned short* Arow = A + (size_t)row0 * GK;
  const unsigned short* Brow = B + (size_t)col0 * GK;

  f32x4 acc[4][4];
  #pragma unroll
  for (int m = 0; m < 4; m++)
    #pragma unroll
    for (int n = 0; n < 4; n++) acc[m][n] = f32x4{0.f,0.f,0.f,0.f};

  for (int k0 = 0; k0 < GK; k0 += 32) {
    #pragma unroll
    for (int i = 0; i < 2; i++) {
      int off = i*4096 + tid*16;        /* byte offset in 8KB tile   */
      int r   = off >> 6;               /* 64B per row (32 bf16)     */
      int ce  = (off & 63) >> 1;        /* element col within K-step */
      gload16((char*)As + off, Arow + (size_t)r*GK + k0 + ce);
      gload16((char*)Bs + off, Brow + (size_t)r*GK + k0 + ce);
    }
    __syncthreads();
    bf16x8 af[4], bf[4];
    #pragma unroll
    for (int m = 0; m < 4; m++)
      af[m] = *(const bf16x8*)&As[(wr*64 + m*16 + la)*32 + hi*8];
    #pragma unroll
    for (int n = 0; n < 4; n++)
      bf[n] = *(const bf16x8*)&Bs[(wc*64 + n*16 + la)*32 + hi*8];
    #pragma unroll
    for (int m = 0; m < 4; m++)
      #pragma unroll
      for (int n = 0; n < 4; n++)
        acc[m][n] = __builtin_amdgcn_mfma_f32_16x16x32_bf16(af[m], bf[n], acc[m][n], 0, 0, 0);
    __syncthreads();
  }

  #pragma unroll
  for (int m = 0; m < 4; m++) {
    #pragma unroll
    for (int n = 0; n < 4; n++) {
      int col = col0 + wc*64 + n*16 + la;
      float bv = bias[col];
      #pragma unroll
      for (int r = 0; r < 4; r++) {
        int row = row0 + wr*64 + m*16 + hi*4 + r;
        float val = acc[m][n][r] + bv;
        if (mode == 0) {
          int b = row >> 11, s = row & (SEQ-1);
          int h = col >> 7,  d = col & (DH-1);
          outb[((size_t)(b*NH + h)*SEQ + s)*DH + d] = f2bf(val);
        } else {
          outf[(size_t)row*D_MODEL + col] = val;
        }
      }
    }
  }
}

/* ---------------- flash attention fwd ----------------
   grid (16 q-tiles, 32 b*h). 4 waves x 32 q-rows. KV tile 64.
   K LDS padded [64][136], V transposed [128][72], P per-wave [32][72]. */
__global__ __launch_bounds__(256) void attn_fwd(
    const unsigned short* __restrict__ Q,
    const unsigned short* __restrict__ K,
    const unsigned short* __restrict__ V,
    unsigned short* __restrict__ O)
{
  __shared__ unsigned short Ks [64*136];
  __shared__ unsigned short VTs[128*72];
  __shared__ unsigned short Ps [4*32*72];

  const int tid  = threadIdx.x;
  const int lane = tid & 63, wid = tid >> 6;
  const int la   = lane & 15, hi = lane >> 4;
  const int bh   = blockIdx.y;
  const int q0   = blockIdx.x * 128;
  const int b    = bh >> 4, h = bh & 15;

  const unsigned short* Qh = Q + (size_t)bh * SEQ * DH;
  const unsigned short* Kh = K + (size_t)bh * SEQ * DH;
  const unsigned short* Vh = V + (size_t)bh * SEQ * DH;

  const int qrow = q0 + wid * 32;

  bf16x8 qf[2][4];
  #pragma unroll
  for (int mi = 0; mi < 2; mi++)
    #pragma unroll
    for (int ks = 0; ks < 4; ks++)
      qf[mi][ks] = *(const bf16x8*)(Qh + (size_t)(qrow + mi*16 + la)*DH + ks*32 + hi*8);

  f32x4 o[2][8];
  float mrun[2][4], lrun[2][4];
  #pragma unroll
  for (int mi = 0; mi < 2; mi++) {
    #pragma unroll
    for (int df = 0; df < 8; df++) o[mi][df] = f32x4{0.f,0.f,0.f,0.f};
    #pragma unroll
    for (int r = 0; r < 4; r++) { mrun[mi][r] = -1e30f; lrun[mi][r] = 0.f; }
  }

  #pragma unroll 1
  for (int kv0 = 0; kv0 < SEQ; kv0 += 64) {
    /* stage K row-major (padded) and V transposed */
    #pragma unroll
    for (int i = 0; i < 4; i++) {
      int idx = i*256 + tid;
      int r = idx >> 4;
      int c = (idx & 15) * 8;
      *(ushort8*)(&Ks[r*136 + c]) = *(const ushort8*)(Kh + (size_t)(kv0 + r)*DH + c);
      ushort8 vv = *(const ushort8*)(Vh + (size_t)(kv0 + r)*DH + c);
      #pragma unroll
      for (int j = 0; j < 8; j++) VTs[(c + j)*72 + r] = vv[j];
    }
    __syncthreads();

    /* S = Q K^T (scaled later) */
    f32x4 S[2][4];
    #pragma unroll
    for (int mi = 0; mi < 2; mi++)
      #pragma unroll
      for (int n = 0; n < 4; n++) S[mi][n] = f32x4{0.f,0.f,0.f,0.f};
    #pragma unroll
    for (int ks = 0; ks < 4; ks++) {
      bf16x8 kf[4];
      #pragma unroll
      for (int n = 0; n < 4; n++)
        kf[n] = *(const bf16x8*)(&Ks[(n*16 + la)*136 + ks*32 + hi*8]);
      #pragma unroll
      for (int mi = 0; mi < 2; mi++)
        #pragma unroll
        for (int n = 0; n < 4; n++)
          S[mi][n] = __builtin_amdgcn_mfma_f32_16x16x32_bf16(qf[mi][ks], kf[n], S[mi][n], 0, 0, 0);
    }

    const float sc = 0.08838834764831845f; /* 1/sqrt(128) */
    #pragma unroll
    for (int mi = 0; mi < 2; mi++)
      #pragma unroll
      for (int n = 0; n < 4; n++)
        #pragma unroll
        for (int r = 0; r < 4; r++) S[mi][n][r] *= sc;

    /* online softmax; rows live in 16-lane groups (same hi) */
    #pragma unroll
    for (int mi = 0; mi < 2; mi++) {
      #pragma unroll
      for (int r = 0; r < 4; r++) {
        float pm = fmaxf(fmaxf(S[mi][0][r], S[mi][1][r]), fmaxf(S[mi][2][r], S[mi][3][r]));
        pm = fmaxf(pm, __shfl_xor(pm, 1));
        pm = fmaxf(pm, __shfl_xor(pm, 2));
        pm = fmaxf(pm, __shfl_xor(pm, 4));
        pm = fmaxf(pm, __shfl_xor(pm, 8));
        float mn = fmaxf(mrun[mi][r], pm);
        float alpha = __expf(mrun[mi][r] - mn);
        mrun[mi][r] = mn;
        float rs = 0.f;
        #pragma unroll
        for (int n = 0; n < 4; n++) {
          float p = __expf(S[mi][n][r] - mn);
          S[mi][n][r] = p;
          rs += p;
        }
        rs += __shfl_xor(rs, 1);
        rs += __shfl_xor(rs, 2);
        rs += __shfl_xor(rs, 4);
        rs += __shfl_xor(rs, 8);
        lrun[mi][r] = lrun[mi][r]*alpha + rs;
        #pragma unroll
        for (int df = 0; df < 8; df++) o[mi][df][r] *= alpha;
      }
    }

    /* P -> LDS (C-layout write), read back in A-layout (per-wave region) */
    const int pbase = wid * 32 * 72;
    #pragma unroll
    for (int mi = 0; mi < 2; mi++)
      #pragma unroll
      for (int n = 0; n < 4; n++)
        #pragma unroll
        for (int r = 0; r < 4; r++)
          Ps[pbase + (mi*16 + hi*4 + r)*72 + n*16 + la] = f2bf(S[mi][n][r]);

    #pragma unroll
    for (int ks2 = 0; ks2 < 2; ks2++) {
      bf16x8 pf[2];
      #pragma unroll
      for (int mi = 0; mi < 2; mi++)
        pf[mi] = *(const bf16x8*)(&Ps[pbase + (mi*16 + la)*72 + ks2*32 + hi*8]);
      #pragma unroll
      for (int df = 0; df < 8; df++) {
        bf16x8 vf = *(const bf16x8*)(&VTs[(df*16 + la)*72 + ks2*32 + hi*8]);
        #pragma unroll
        for (int mi = 0; mi < 2; mi++)
          o[mi][df] = __builtin_amdgcn_mfma_f32_16x16x32_bf16(pf[mi], vf, o[mi][df], 0, 0, 0);
      }
    }
    __syncthreads();
  }

  /* epilogue: O[b][s][h*128+d] bf16 */
  unsigned short* Ob = O + (size_t)b * SEQ * D_MODEL + h * DH;
  #pragma unroll
  for (int mi = 0; mi < 2; mi++)
    #pragma unroll
    for (int df = 0; df < 8; df++)
      #pragma unroll
      for (int r = 0; r < 4; r++) {
        int srow = qrow + mi*16 + hi*4 + r;
        float val = o[mi][df][r] / lrun[mi][r];
        Ob[(size_t)srow * D_MODEL + df*16 + la] = f2bf(val);
      }
}

/* ---------------- launcher ---------------- */
extern "C" void kernel_launch(void* const* d_in, const int* in_sizes, int n_in,
                              void* d_out, int out_size, void* d_ws, size_t ws_size,
                              hipStream_t stream) {
  const float* x  = (const float*)d_in[0];
  const float* wq = (const float*)d_in[1];
  const float* bq = (const float*)d_in[2];
  const float* wk = (const float*)d_in[3];
  const float* bk = (const float*)d_in[4];
  const float* wv = (const float*)d_in[5];
  const float* bv = (const float*)d_in[6];
  const float* wo = (const float*)d_in[7];
  const float* bo = (const float*)d_in[8];
  float* out = (float*)d_out;

  const size_t X = (size_t)MROWS * D_MODEL;   /* 8388608  */
  const size_t W = (size_t)D_MODEL * D_MODEL; /* 4194304  */

  unsigned short* ws  = (unsigned short*)d_ws;
  unsigned short* xb  = ws;
  unsigned short* wqb = xb  + X;
  unsigned short* wkb = wqb + W;
  unsigned short* wvb = wkb + W;
  unsigned short* wob = wvb + W;
  unsigned short* qb  = wob + W;
  unsigned short* kb  = qb  + X;
  unsigned short* vb  = kb  + X;
  unsigned short* ab  = vb  + X;

  cast_f32_bf16<<<dim3((unsigned)(X/2048)), 256, 0, stream>>>(x,  xb);
  cast_f32_bf16<<<dim3((unsigned)(W/2048)), 256, 0, stream>>>(wq, wqb);
  cast_f32_bf16<<<dim3((unsigned)(W/2048)), 256, 0, stream>>>(wk, wkb);
  cast_f32_bf16<<<dim3((unsigned)(W/2048)), 256, 0, stream>>>(wv, wvb);
  cast_f32_bf16<<<dim3((unsigned)(W/2048)), 256, 0, stream>>>(wo, wob);

  dim3 ggrid(D_MODEL/128, MROWS/128);  /* 16 x 32 */
  gemm_bt<<<ggrid, 256, 0, stream>>>(xb, wqb, bq, qb, nullptr, 0);
  gemm_bt<<<ggrid, 256, 0, stream>>>(xb, wkb, bk, kb, nullptr, 0);
  gemm_bt<<<ggrid, 256, 0, stream>>>(xb, wvb, bv, vb, nullptr, 0);

  attn_fwd<<<dim3(SEQ/128, NB*NH), 256, 0, stream>>>(qb, kb, vb, ab);

  gemm_bt<<<ggrid, 256, 0, stream>>>(ab, wob, bo, nullptr, out, 1);
}